// Round 6
// baseline (3186.361 us; speedup 1.0000x reference)
//
#include <hip/hip_runtime.h>

#define H 64
#define MAXW 256        // max windows (scan width)
#define WSH 10          // 1024 nodes per window -> W = ceil(200000/1024) = 196 <= MAXW
#define WNODES (1 << WSH)
#define BINCH 4096      // edges per k_bin block
#define BPT (BINCH / 256)

// ---------- window counting (LDS-aggregated; ~200 global atomics/block) ----------
__global__ __launch_bounds__(256) void k_wincount(const int* __restrict__ ei, int E,
                                                  int* __restrict__ winS, int* __restrict__ winD) {
    __shared__ int hs[MAXW], hd[MAXW];
    hs[threadIdx.x] = 0; hd[threadIdx.x] = 0;
    __syncthreads();
    int stride = gridDim.x * 256;
    for (int e = blockIdx.x * 256 + threadIdx.x; e < E; e += stride) {
        atomicAdd(&hs[ei[e] >> WSH], 1);
        atomicAdd(&hd[ei[E + e] >> WSH], 1);
    }
    __syncthreads();
    if (hs[threadIdx.x]) atomicAdd(&winS[threadIdx.x], hs[threadIdx.x]);
    if (hd[threadIdx.x]) atomicAdd(&winD[threadIdx.x], hd[threadIdx.x]);
}

// Single block: exclusive scan of both window-count arrays (MAXW wide, zero-padded).
__global__ void k_scan_win(const int* __restrict__ winS, const int* __restrict__ winD,
                           int* __restrict__ baseS, int* __restrict__ baseD,
                           int* __restrict__ curS, int* __restrict__ curD) {
    __shared__ int s[256];
    int tid = threadIdx.x;
    int v = winS[tid];
    s[tid] = v; __syncthreads();
    for (int off = 1; off < 256; off <<= 1) {
        int t = (tid >= off) ? s[tid - off] : 0; __syncthreads();
        s[tid] += t; __syncthreads();
    }
    int ex = s[tid] - v;
    baseS[tid] = ex; curS[tid] = ex;
    if (tid == 255) baseS[256] = s[255];
    __syncthreads();
    v = winD[tid];
    s[tid] = v; __syncthreads();
    for (int off = 1; off < 256; off <<= 1) {
        int t = (tid >= off) ? s[tid - off] : 0; __syncthreads();
        s[tid] += t; __syncthreads();
    }
    ex = s[tid] - v;
    baseD[tid] = ex; curD[tid] = ex;
    if (tid == 255) baseD[256] = s[255];
}

// ---------- bin: LDS counting-sort of a 4096-edge chunk by window, coalesced flush ----------
__global__ __launch_bounds__(256) void k_bin(const int* __restrict__ ei, int E,
                                             int* __restrict__ gcurS, int* __restrict__ gcurD,
                                             int2* __restrict__ bufS, int2* __restrict__ bufD) {
    __shared__ int hist[MAXW];
    __shared__ int lbase[MAXW];
    __shared__ int lcur[MAXW];
    __shared__ int gdelta[MAXW];
    __shared__ int2 rec[BINCH];
    __shared__ unsigned char wid[BINCH];
    __shared__ int sscan[256];

    int tid = threadIdx.x;
    int e0 = blockIdx.x * BINCH;
    int n = min(BINCH, E - e0);

    for (int dir = 0; dir < 2; ++dir) {
        int* gcur = dir ? gcurD : gcurS;
        int2* buf = dir ? bufD : bufS;
        hist[tid] = 0;
        __syncthreads();
        int kk[BPT], vv[BPT];
#pragma unroll
        for (int j = 0; j < BPT; ++j) {
            int idx = tid + j * 256;
            if (idx < n) {
                int e = e0 + idx;
                int a = ei[e], b = ei[E + e];
                kk[j] = dir ? b : a;
                vv[j] = dir ? a : b;
                atomicAdd(&hist[kk[j] >> WSH], 1);
            }
        }
        __syncthreads();
        {   // exclusive scan of hist
            int hv = hist[tid];
            sscan[tid] = hv; __syncthreads();
            for (int off = 1; off < 256; off <<= 1) {
                int t = (tid >= off) ? sscan[tid - off] : 0; __syncthreads();
                sscan[tid] += t; __syncthreads();
            }
            lbase[tid] = sscan[tid] - hv;
            lcur[tid] = lbase[tid];
        }
        __syncthreads();
#pragma unroll
        for (int j = 0; j < BPT; ++j) {
            int idx = tid + j * 256;
            if (idx < n) {
                int w = kk[j] >> WSH;
                int p = atomicAdd(&lcur[w], 1);
                rec[p] = make_int2(kk[j], vv[j]);
                wid[p] = (unsigned char)w;
            }
        }
        __syncthreads();
        {   // reserve one contiguous global chunk per non-empty window
            int c = hist[tid];
            int g = c ? atomicAdd(&gcur[tid], c) : 0;
            gdelta[tid] = g - lbase[tid];
        }
        __syncthreads();
        for (int j = tid; j < n; j += 256) {   // coalesced flush (runs sorted by window)
            int w = wid[j];
            int2 r = rec[j];
            *(long long*)&buf[gdelta[w] + j] = *(long long*)&r;
        }
        __syncthreads();
    }
}

// ---------- per-window degree histogram (LDS table, coalesced deg write) ----------
__global__ __launch_bounds__(256) void k_degwin(const int2* __restrict__ bufS,
                                                const int2* __restrict__ bufD,
                                                const int* __restrict__ baseS,
                                                const int* __restrict__ baseD,
                                                int* __restrict__ degS, int* __restrict__ degD,
                                                int Ns, int Nd, int W) {
    __shared__ int h[WNODES];
    int b = blockIdx.x;
    int dir = (b >= W) ? 1 : 0;
    int w = dir ? b - W : b;
    const int2* buf = dir ? bufD : bufS;
    const int* base = dir ? baseD : baseS;
    int* deg = dir ? degD : degS;
    int N = dir ? Nd : Ns;
    int lo = w << WSH;
    int hi = min(lo + WNODES, N);
    for (int i = threadIdx.x; i < WNODES; i += 256) h[i] = 0;
    __syncthreads();
    int beg = base[w], end = base[w + 1];
    for (int r = beg + threadIdx.x; r < end; r += 256)
        atomicAdd(&h[buf[r].x - lo], 1);
    __syncthreads();
    for (int i = lo + threadIdx.x; i < hi; i += 256) deg[i] = h[i - lo];
}

// ---------- per-window CSR scatter (LDS cursors; writes confined to ~80KB segment) ----------
__global__ __launch_bounds__(256) void k_scatwin(const int2* __restrict__ bufS,
                                                 const int2* __restrict__ bufD,
                                                 const int* __restrict__ baseS,
                                                 const int* __restrict__ baseD,
                                                 const int* __restrict__ rpS,
                                                 const int* __restrict__ rpD,
                                                 int* __restrict__ colS, int* __restrict__ colD,
                                                 int Ns, int Nd, int W) {
    __shared__ int cur[WNODES];
    int b = blockIdx.x;
    int dir = (b >= W) ? 1 : 0;
    int w = dir ? b - W : b;
    const int2* buf = dir ? bufD : bufS;
    const int* base = dir ? baseD : baseS;
    const int* rp = dir ? rpD : rpS;
    int* col = dir ? colD : colS;
    int N = dir ? Nd : Ns;
    int lo = w << WSH;
    int hi = min(lo + WNODES, N);
    for (int i = lo + threadIdx.x; i < hi; i += 256) cur[i - lo] = rp[i];
    __syncthreads();
    int beg = base[w], end = base[w + 1];
    for (int r = beg + threadIdx.x; r < end; r += 256) {
        int2 rc = buf[r];
        int p = atomicAdd(&cur[rc.x - lo], 1);
        col[p] = rc.y;
    }
}

// ---------- deg -> rp scans ----------
__global__ void k_chunk_sums(const int* __restrict__ deg, int n, int* __restrict__ bsum) {
    __shared__ int s[256];
    int tid = threadIdx.x;
    int base = blockIdx.x * 1024 + tid * 4;
    int t = 0;
#pragma unroll
    for (int j = 0; j < 4; ++j) { int i = base + j; if (i < n) t += deg[i]; }
    s[tid] = t; __syncthreads();
    for (int off = 128; off > 0; off >>= 1) {
        if (tid < off) s[tid] += s[tid + off];
        __syncthreads();
    }
    if (tid == 0) bsum[blockIdx.x] = s[0];
}

__global__ void k_scan_bsums(int* __restrict__ bsum, int nb, int* __restrict__ rp, int n) {
    __shared__ int s[256];
    int tid = threadIdx.x;
    int v = (tid < nb) ? bsum[tid] : 0;
    s[tid] = v; __syncthreads();
    for (int off = 1; off < 256; off <<= 1) {
        int t = (tid >= off) ? s[tid - off] : 0; __syncthreads();
        s[tid] += t; __syncthreads();
    }
    if (tid < nb) bsum[tid] = s[tid] - v;
    if (tid == 255) rp[n] = s[255];
}

__global__ void k_scan_final(const int* __restrict__ deg, int n,
                             const int* __restrict__ bsum, int* __restrict__ rp) {
    __shared__ int s[256];
    int tid = threadIdx.x;
    int base = blockIdx.x * 1024 + tid * 4;
    int v[4]; int t = 0;
#pragma unroll
    for (int j = 0; j < 4; ++j) { int i = base + j; v[j] = (i < n) ? deg[i] : 0; t += v[j]; }
    s[tid] = t; __syncthreads();
    for (int off = 1; off < 256; off <<= 1) {
        int x = (tid >= off) ? s[tid - off] : 0; __syncthreads();
        s[tid] += x; __syncthreads();
    }
    int excl = s[tid] - t + bsum[blockIdx.x];
#pragma unroll
    for (int j = 0; j < 4; ++j) { int i = base + j; if (i < n) rp[i] = excl; excl += v[j]; }
}

// ---------- feature init ----------
__global__ void k_init_x(const int* __restrict__ uid, const int* __restrict__ rid,
                         const float* __restrict__ recipe_x,
                         const float* __restrict__ user_emb, const float* __restrict__ recipe_emb,
                         const float* __restrict__ lin_w, const float* __restrict__ lin_b,
                         float* __restrict__ x_user, float* __restrict__ x_recipe,
                         int Nu, int Nr) {
    int n = blockIdx.x, h = threadIdx.x;
    __shared__ float rx[10];
    if (n < Nr && h < 10) rx[h] = recipe_x[(size_t)n * 10 + h];
    __syncthreads();
    if (n < Nr) {
        float o = lin_b[h];
#pragma unroll
        for (int k = 0; k < 10; ++k) o = fmaf(rx[k], lin_w[k * H + h], o);
        o += recipe_emb[(size_t)rid[n] * H + h];
        x_recipe[(size_t)n * H + h] = o;
    }
    if (n < Nu) {
        x_user[(size_t)n * H + h] = user_emb[(size_t)uid[n] * H + h];
    }
}

// ---------- SAGE layer ----------
// One wave per FOUR dst nodes: gather phase per node (R4's 16-deep ILP layout,
// lane=(g,c): g=edge group, c=feature quad), then ONE epilogue pass where each
// Wl/Wr row load (256B, L1) serves 4 matvecs. This cuts the W-read L1 traffic
// from 32KB/node to 8KB/node (it was ~6.5GB/pass, ~55% of L1 cycles).
// mean/x_dst come from LDS same-address broadcasts (conflict-free).
template <bool RELU>
__global__ __launch_bounds__(256) void k_sage(const float* __restrict__ x_src,
                                              const float* __restrict__ x_dst,
                                              const int* __restrict__ rp,
                                              const int* __restrict__ col,
                                              const float* __restrict__ Wl,
                                              const float* __restrict__ bl,
                                              const float* __restrict__ Wr,
                                              float* __restrict__ out, int n_dst) {
    int wave = threadIdx.x >> 6, lane = threadIdx.x & 63;
    int c = lane & 15, g = lane >> 4;
    int n0 = (blockIdx.x * 4 + wave) * 4;
    __shared__ float sm[4][4][H];   // [wave][node][feature] mean
    __shared__ float sx[4][4][H];   // [wave][node][feature] x_dst

#pragma unroll
    for (int j = 0; j < 4; ++j) {
        int n = n0 + j;
        if (n < n_dst) {
            int beg = rp[n], end = rp[n + 1];
            float xdv = x_dst[(size_t)n * H + lane];   // hoisted: overlaps gather
            float4 a0 = make_float4(0.f, 0.f, 0.f, 0.f);
            float4 a1 = a0, a2 = a0, a3 = a0;
            int e = beg + g;
            for (; e + 12 < end; e += 16) {
                int r0 = col[e];
                int r1 = col[e + 4];
                int r2 = col[e + 8];
                int r3 = col[e + 12];
                float4 v0 = *((const float4*)(x_src + (size_t)r0 * H) + c);
                float4 v1 = *((const float4*)(x_src + (size_t)r1 * H) + c);
                float4 v2 = *((const float4*)(x_src + (size_t)r2 * H) + c);
                float4 v3 = *((const float4*)(x_src + (size_t)r3 * H) + c);
                a0.x += v0.x; a0.y += v0.y; a0.z += v0.z; a0.w += v0.w;
                a1.x += v1.x; a1.y += v1.y; a1.z += v1.z; a1.w += v1.w;
                a2.x += v2.x; a2.y += v2.y; a2.z += v2.z; a2.w += v2.w;
                a3.x += v3.x; a3.y += v3.y; a3.z += v3.z; a3.w += v3.w;
            }
            for (; e < end; e += 4) {
                int r = col[e];
                float4 v = *((const float4*)(x_src + (size_t)r * H) + c);
                a0.x += v.x; a0.y += v.y; a0.z += v.z; a0.w += v.w;
            }
            float4 acc = make_float4((a0.x + a1.x) + (a2.x + a3.x),
                                     (a0.y + a1.y) + (a2.y + a3.y),
                                     (a0.z + a1.z) + (a2.z + a3.z),
                                     (a0.w + a1.w) + (a2.w + a3.w));
#pragma unroll
            for (int off = 16; off < 64; off <<= 1) {
                acc.x += __shfl_xor(acc.x, off);
                acc.y += __shfl_xor(acc.y, off);
                acc.z += __shfl_xor(acc.z, off);
                acc.w += __shfl_xor(acc.w, off);
            }
            float inv = 1.0f / fmaxf((float)(end - beg), 1.0f);
            if (g == 0) {
                float4 mv = make_float4(acc.x * inv, acc.y * inv, acc.z * inv, acc.w * inv);
                *((float4*)&sm[wave][j][c * 4]) = mv;
            }
            sx[wave][j][lane] = xdv;
        }
    }
    __syncthreads();   // one barrier per 16 nodes (was per 4)

    if (n0 < n_dst) {
        float b = bl[lane];
        float o0 = b, o1 = b, o2 = b, o3 = b;
        const float4* m0 = (const float4*)sm[wave][0];
        const float4* m1 = (const float4*)sm[wave][1];
        const float4* m2 = (const float4*)sm[wave][2];
        const float4* m3 = (const float4*)sm[wave][3];
        const float4* x0 = (const float4*)sx[wave][0];
        const float4* x1 = (const float4*)sx[wave][1];
        const float4* x2 = (const float4*)sx[wave][2];
        const float4* x3 = (const float4*)sx[wave][3];
#pragma unroll
        for (int k4 = 0; k4 < 16; ++k4) {
            float4 mm0 = m0[k4], mm1 = m1[k4], mm2 = m2[k4], mm3 = m3[k4];
            float4 xx0 = x0[k4], xx1 = x1[k4], xx2 = x2[k4], xx3 = x3[k4];
#pragma unroll
            for (int r = 0; r < 4; ++r) {
                int k = k4 * 4 + r;
                float wl = Wl[k * H + lane];    // one 256B L1 load serves 4 nodes
                float wr = Wr[k * H + lane];
                float mr0 = (&mm0.x)[r], mr1 = (&mm1.x)[r], mr2 = (&mm2.x)[r], mr3 = (&mm3.x)[r];
                float xr0 = (&xx0.x)[r], xr1 = (&xx1.x)[r], xr2 = (&xx2.x)[r], xr3 = (&xx3.x)[r];
                o0 = fmaf(mr0, wl, o0); o0 = fmaf(xr0, wr, o0);
                o1 = fmaf(mr1, wl, o1); o1 = fmaf(xr1, wr, o1);
                o2 = fmaf(mr2, wl, o2); o2 = fmaf(xr2, wr, o2);
                o3 = fmaf(mr3, wl, o3); o3 = fmaf(xr3, wr, o3);
            }
        }
        if (RELU) {
            o0 = fmaxf(o0, 0.f); o1 = fmaxf(o1, 0.f);
            o2 = fmaxf(o2, 0.f); o3 = fmaxf(o3, 0.f);
        }
        out[(size_t)n0 * H + lane] = o0;
        if (n0 + 1 < n_dst) out[(size_t)(n0 + 1) * H + lane] = o1;
        if (n0 + 2 < n_dst) out[(size_t)(n0 + 2) * H + lane] = o2;
        if (n0 + 3 < n_dst) out[(size_t)(n0 + 3) * H + lane] = o3;
    }
}

// ---------- classifier ----------
__global__ __launch_bounds__(256) void k_dot(const float* __restrict__ xu,
                                             const float* __restrict__ xr,
                                             const int* __restrict__ eli,
                                             float* __restrict__ out, int L) {
    long long w = (blockIdx.x * (long long)blockDim.x + threadIdx.x) >> 6;
    int lane = threadIdx.x & 63;
    int c = lane & 15, g = lane >> 4;
    long long e = w * 4 + g;
    if (e >= L) return;
    int a = eli[e], b = eli[(long long)L + e];
    float4 u = *((const float4*)(xu + (size_t)a * H) + c);
    float4 r = *((const float4*)(xr + (size_t)b * H) + c);
    float p = u.x * r.x;
    p = fmaf(u.y, r.y, p);
    p = fmaf(u.z, r.z, p);
    p = fmaf(u.w, r.w, p);
#pragma unroll
    for (int off = 1; off < 16; off <<= 1) p += __shfl_xor(p, off);
    if (c == 0) out[e] = p;
}

extern "C" void kernel_launch(void* const* d_in, const int* in_sizes, int n_in,
                              void* d_out, int out_size, void* d_ws, size_t ws_size,
                              hipStream_t stream) {
    const int*   uid        = (const int*)d_in[0];
    const int*   rid        = (const int*)d_in[1];
    const float* recipe_x   = (const float*)d_in[2];
    const int*   ei         = (const int*)d_in[3];
    const int*   eli        = (const int*)d_in[4];
    const float* user_emb   = (const float*)d_in[5];
    const float* recipe_emb = (const float*)d_in[6];
    const float* lin_w      = (const float*)d_in[7];
    const float* lin_b      = (const float*)d_in[8];
    const float* Wl         = (const float*)d_in[9];
    const float* bl         = (const float*)d_in[10];
    const float* Wr         = (const float*)d_in[11];

    const int Nu = in_sizes[0], Nr = in_sizes[1];
    const int E = in_sizes[3] / 2, L = in_sizes[4] / 2;
    const int nmax = (Nu > Nr) ? Nu : Nr;
    const int W = ((nmax - 1) >> WSH) + 1;   // 196 for N=200000

    char* ws = (char*)d_ws;
    size_t off = 0;
    auto alloc = [&](size_t bytes) -> char* {
        char* p = ws + off;
        off += (bytes + 255) & ~(size_t)255;
        return p;
    };
    float* x_user   = (float*)alloc((size_t)Nu * H * 4);
    float* x_recipe = (float*)alloc((size_t)Nr * H * 4);
    // overlay: y buffers (needed from sage on) share space with bin buffers (dead by then)
    size_t ybytes  = ((size_t)Nu + Nr) * H * 4;
    size_t bbytes  = (size_t)E * 8 * 2;
    char* region   = alloc(ybytes > bbytes ? ybytes : bbytes);
    float* y_user   = (float*)region;
    float* y_recipe = (float*)(region + (size_t)Nu * H * 4);
    int2* bufS = (int2*)region;
    int2* bufD = (int2*)(region + (size_t)E * 8);
    int* deg_src = (int*)alloc((size_t)Nu * 4);
    int* deg_dst = (int*)alloc((size_t)Nr * 4);
    int* rp_src  = (int*)alloc((size_t)(Nu + 1) * 4);
    int* rp_dst  = (int*)alloc((size_t)(Nr + 1) * 4);
    int* col_src = (int*)alloc((size_t)E * 4);
    int* col_dst = (int*)alloc((size_t)E * 4);
    int* winS  = (int*)alloc(MAXW * 4);      // winS..winD adjacent: one memset
    int* winD  = (int*)alloc(MAXW * 4);
    int* baseS = (int*)alloc((MAXW + 1) * 4);
    int* baseD = (int*)alloc((MAXW + 1) * 4);
    int* curS  = (int*)alloc(MAXW * 4);
    int* curD  = (int*)alloc(MAXW * 4);
    int* bsum  = (int*)alloc(4096);
    (void)ws_size; (void)n_in; (void)out_size;

    // zero window counters (ws is poisoned 0xAA)
    hipMemsetAsync(winS, 0, (size_t)2 * MAXW * 4, stream);

    // CSR build: count -> scan -> bin -> per-window deg -> rp -> per-window scatter
    k_wincount<<<1024, 256, 0, stream>>>(ei, E, winS, winD);
    k_scan_win<<<1, 256, 0, stream>>>(winS, winD, baseS, baseD, curS, curD);
    k_bin<<<(E + BINCH - 1) / BINCH, 256, 0, stream>>>(ei, E, curS, curD, bufS, bufD);
    k_degwin<<<2 * W, 256, 0, stream>>>(bufS, bufD, baseS, baseD, deg_src, deg_dst, Nu, Nr, W);

    int nb_s = (Nu + 1023) / 1024, nb_d = (Nr + 1023) / 1024;
    k_chunk_sums<<<nb_s, 256, 0, stream>>>(deg_src, Nu, bsum);
    k_scan_bsums<<<1, 256, 0, stream>>>(bsum, nb_s, rp_src, Nu);
    k_scan_final<<<nb_s, 256, 0, stream>>>(deg_src, Nu, bsum, rp_src);
    k_chunk_sums<<<nb_d, 256, 0, stream>>>(deg_dst, Nr, bsum);
    k_scan_bsums<<<1, 256, 0, stream>>>(bsum, nb_d, rp_dst, Nr);
    k_scan_final<<<nb_d, 256, 0, stream>>>(deg_dst, Nr, bsum, rp_dst);

    k_scatwin<<<2 * W, 256, 0, stream>>>(bufS, bufD, baseS, baseD, rp_src, rp_dst,
                                         col_src, col_dst, Nu, Nr, W);

    // initial features
    k_init_x<<<nmax, 64, 0, stream>>>(uid, rid, recipe_x, user_emb, recipe_emb,
                                      lin_w, lin_b, x_user, x_recipe, Nu, Nr);

    // layer 0 (+ReLU): 16 nodes per block (4 waves x 4 nodes)
    k_sage<true><<<(Nr + 15) / 16, 256, 0, stream>>>(x_user, x_recipe, rp_dst, col_dst,
                                                     Wl + 0 * H * H, bl + 0 * H, Wr + 0 * H * H,
                                                     y_recipe, Nr);
    k_sage<true><<<(Nu + 15) / 16, 256, 0, stream>>>(x_recipe, x_user, rp_src, col_src,
                                                     Wl + 1 * H * H, bl + 1 * H, Wr + 1 * H * H,
                                                     y_user, Nu);
    // layer 1 (no ReLU)
    k_sage<false><<<(Nr + 15) / 16, 256, 0, stream>>>(y_user, y_recipe, rp_dst, col_dst,
                                                      Wl + 2 * H * H, bl + 2 * H, Wr + 2 * H * H,
                                                      x_recipe, Nr);
    k_sage<false><<<(Nu + 15) / 16, 256, 0, stream>>>(y_recipe, y_user, rp_src, col_src,
                                                      Wl + 3 * H * H, bl + 3 * H, Wr + 3 * H * H,
                                                      x_user, Nu);

    // classifier
    long long nwaves = ((long long)L + 3) / 4;
    long long nblk = (nwaves + 3) / 4;
    k_dot<<<(int)nblk, 256, 0, stream>>>(x_user, x_recipe, eli, (float*)d_out, L);
}

// Round 7
// 1258.408 us; speedup vs baseline: 2.5321x; 2.5321x over previous
//
#include <hip/hip_runtime.h>

#define H 64
#define MAXW 256        // max windows (scan width)
#define WSH 10          // 1024 nodes per window -> W = ceil(200000/1024) = 196 <= MAXW
#define WNODES (1 << WSH)
#define BINCH 4096      // edges per k_bin block
#define BPT (BINCH / 256)

// ---------- window counting (LDS-aggregated; ~200 global atomics/block) ----------
__global__ __launch_bounds__(256) void k_wincount(const int* __restrict__ ei, int E,
                                                  int* __restrict__ winS, int* __restrict__ winD) {
    __shared__ int hs[MAXW], hd[MAXW];
    hs[threadIdx.x] = 0; hd[threadIdx.x] = 0;
    __syncthreads();
    int stride = gridDim.x * 256;
    for (int e = blockIdx.x * 256 + threadIdx.x; e < E; e += stride) {
        atomicAdd(&hs[ei[e] >> WSH], 1);
        atomicAdd(&hd[ei[E + e] >> WSH], 1);
    }
    __syncthreads();
    if (hs[threadIdx.x]) atomicAdd(&winS[threadIdx.x], hs[threadIdx.x]);
    if (hd[threadIdx.x]) atomicAdd(&winD[threadIdx.x], hd[threadIdx.x]);
}

// Single block: exclusive scan of both window-count arrays (MAXW wide, zero-padded).
__global__ void k_scan_win(const int* __restrict__ winS, const int* __restrict__ winD,
                           int* __restrict__ baseS, int* __restrict__ baseD,
                           int* __restrict__ curS, int* __restrict__ curD) {
    __shared__ int s[256];
    int tid = threadIdx.x;
    int v = winS[tid];
    s[tid] = v; __syncthreads();
    for (int off = 1; off < 256; off <<= 1) {
        int t = (tid >= off) ? s[tid - off] : 0; __syncthreads();
        s[tid] += t; __syncthreads();
    }
    int ex = s[tid] - v;
    baseS[tid] = ex; curS[tid] = ex;
    if (tid == 255) baseS[256] = s[255];
    __syncthreads();
    v = winD[tid];
    s[tid] = v; __syncthreads();
    for (int off = 1; off < 256; off <<= 1) {
        int t = (tid >= off) ? s[tid - off] : 0; __syncthreads();
        s[tid] += t; __syncthreads();
    }
    ex = s[tid] - v;
    baseD[tid] = ex; curD[tid] = ex;
    if (tid == 255) baseD[256] = s[255];
}

// ---------- bin: LDS counting-sort of a 4096-edge chunk by window, coalesced flush ----------
__global__ __launch_bounds__(256) void k_bin(const int* __restrict__ ei, int E,
                                             int* __restrict__ gcurS, int* __restrict__ gcurD,
                                             int2* __restrict__ bufS, int2* __restrict__ bufD) {
    __shared__ int hist[MAXW];
    __shared__ int lbase[MAXW];
    __shared__ int lcur[MAXW];
    __shared__ int gdelta[MAXW];
    __shared__ int2 rec[BINCH];
    __shared__ unsigned char wid[BINCH];
    __shared__ int sscan[256];

    int tid = threadIdx.x;
    int e0 = blockIdx.x * BINCH;
    int n = min(BINCH, E - e0);

    for (int dir = 0; dir < 2; ++dir) {
        int* gcur = dir ? gcurD : gcurS;
        int2* buf = dir ? bufD : bufS;
        hist[tid] = 0;
        __syncthreads();
        int kk[BPT], vv[BPT];
#pragma unroll
        for (int j = 0; j < BPT; ++j) {
            int idx = tid + j * 256;
            if (idx < n) {
                int e = e0 + idx;
                int a = ei[e], b = ei[E + e];
                kk[j] = dir ? b : a;
                vv[j] = dir ? a : b;
                atomicAdd(&hist[kk[j] >> WSH], 1);
            }
        }
        __syncthreads();
        {   // exclusive scan of hist
            int hv = hist[tid];
            sscan[tid] = hv; __syncthreads();
            for (int off = 1; off < 256; off <<= 1) {
                int t = (tid >= off) ? sscan[tid - off] : 0; __syncthreads();
                sscan[tid] += t; __syncthreads();
            }
            lbase[tid] = sscan[tid] - hv;
            lcur[tid] = lbase[tid];
        }
        __syncthreads();
#pragma unroll
        for (int j = 0; j < BPT; ++j) {
            int idx = tid + j * 256;
            if (idx < n) {
                int w = kk[j] >> WSH;
                int p = atomicAdd(&lcur[w], 1);
                rec[p] = make_int2(kk[j], vv[j]);
                wid[p] = (unsigned char)w;
            }
        }
        __syncthreads();
        {   // reserve one contiguous global chunk per non-empty window
            int c = hist[tid];
            int g = c ? atomicAdd(&gcur[tid], c) : 0;
            gdelta[tid] = g - lbase[tid];
        }
        __syncthreads();
        for (int j = tid; j < n; j += 256) {   // coalesced flush (runs sorted by window)
            int w = wid[j];
            int2 r = rec[j];
            *(long long*)&buf[gdelta[w] + j] = *(long long*)&r;
        }
        __syncthreads();
    }
}

// ---------- per-window degree histogram (LDS table, coalesced deg write) ----------
__global__ __launch_bounds__(256) void k_degwin(const int2* __restrict__ bufS,
                                                const int2* __restrict__ bufD,
                                                const int* __restrict__ baseS,
                                                const int* __restrict__ baseD,
                                                int* __restrict__ degS, int* __restrict__ degD,
                                                int Ns, int Nd, int W) {
    __shared__ int h[WNODES];
    int b = blockIdx.x;
    int dir = (b >= W) ? 1 : 0;
    int w = dir ? b - W : b;
    const int2* buf = dir ? bufD : bufS;
    const int* base = dir ? baseD : baseS;
    int* deg = dir ? degD : degS;
    int N = dir ? Nd : Ns;
    int lo = w << WSH;
    int hi = min(lo + WNODES, N);
    for (int i = threadIdx.x; i < WNODES; i += 256) h[i] = 0;
    __syncthreads();
    int beg = base[w], end = base[w + 1];
    for (int r = beg + threadIdx.x; r < end; r += 256)
        atomicAdd(&h[buf[r].x - lo], 1);
    __syncthreads();
    for (int i = lo + threadIdx.x; i < hi; i += 256) deg[i] = h[i - lo];
}

// ---------- per-window CSR scatter (LDS cursors; writes confined to ~80KB segment) ----------
__global__ __launch_bounds__(256) void k_scatwin(const int2* __restrict__ bufS,
                                                 const int2* __restrict__ bufD,
                                                 const int* __restrict__ baseS,
                                                 const int* __restrict__ baseD,
                                                 const int* __restrict__ rpS,
                                                 const int* __restrict__ rpD,
                                                 int* __restrict__ colS, int* __restrict__ colD,
                                                 int Ns, int Nd, int W) {
    __shared__ int cur[WNODES];
    int b = blockIdx.x;
    int dir = (b >= W) ? 1 : 0;
    int w = dir ? b - W : b;
    const int2* buf = dir ? bufD : bufS;
    const int* base = dir ? baseD : baseS;
    const int* rp = dir ? rpD : rpS;
    int* col = dir ? colD : colS;
    int N = dir ? Nd : Ns;
    int lo = w << WSH;
    int hi = min(lo + WNODES, N);
    for (int i = lo + threadIdx.x; i < hi; i += 256) cur[i - lo] = rp[i];
    __syncthreads();
    int beg = base[w], end = base[w + 1];
    for (int r = beg + threadIdx.x; r < end; r += 256) {
        int2 rc = buf[r];
        int p = atomicAdd(&cur[rc.x - lo], 1);
        col[p] = rc.y;
    }
}

// ---------- deg -> rp scans ----------
__global__ void k_chunk_sums(const int* __restrict__ deg, int n, int* __restrict__ bsum) {
    __shared__ int s[256];
    int tid = threadIdx.x;
    int base = blockIdx.x * 1024 + tid * 4;
    int t = 0;
#pragma unroll
    for (int j = 0; j < 4; ++j) { int i = base + j; if (i < n) t += deg[i]; }
    s[tid] = t; __syncthreads();
    for (int off = 128; off > 0; off >>= 1) {
        if (tid < off) s[tid] += s[tid + off];
        __syncthreads();
    }
    if (tid == 0) bsum[blockIdx.x] = s[0];
}

__global__ void k_scan_bsums(int* __restrict__ bsum, int nb, int* __restrict__ rp, int n) {
    __shared__ int s[256];
    int tid = threadIdx.x;
    int v = (tid < nb) ? bsum[tid] : 0;
    s[tid] = v; __syncthreads();
    for (int off = 1; off < 256; off <<= 1) {
        int t = (tid >= off) ? s[tid - off] : 0; __syncthreads();
        s[tid] += t; __syncthreads();
    }
    if (tid < nb) bsum[tid] = s[tid] - v;
    if (tid == 255) rp[n] = s[255];
}

__global__ void k_scan_final(const int* __restrict__ deg, int n,
                             const int* __restrict__ bsum, int* __restrict__ rp) {
    __shared__ int s[256];
    int tid = threadIdx.x;
    int base = blockIdx.x * 1024 + tid * 4;
    int v[4]; int t = 0;
#pragma unroll
    for (int j = 0; j < 4; ++j) { int i = base + j; v[j] = (i < n) ? deg[i] : 0; t += v[j]; }
    s[tid] = t; __syncthreads();
    for (int off = 1; off < 256; off <<= 1) {
        int x = (tid >= off) ? s[tid - off] : 0; __syncthreads();
        s[tid] += x; __syncthreads();
    }
    int excl = s[tid] - t + bsum[blockIdx.x];
#pragma unroll
    for (int j = 0; j < 4; ++j) { int i = base + j; if (i < n) rp[i] = excl; excl += v[j]; }
}

// ---------- feature init ----------
__global__ void k_init_x(const int* __restrict__ uid, const int* __restrict__ rid,
                         const float* __restrict__ recipe_x,
                         const float* __restrict__ user_emb, const float* __restrict__ recipe_emb,
                         const float* __restrict__ lin_w, const float* __restrict__ lin_b,
                         float* __restrict__ x_user, float* __restrict__ x_recipe,
                         int Nu, int Nr) {
    int n = blockIdx.x, h = threadIdx.x;
    __shared__ float rx[10];
    if (n < Nr && h < 10) rx[h] = recipe_x[(size_t)n * 10 + h];
    __syncthreads();
    if (n < Nr) {
        float o = lin_b[h];
#pragma unroll
        for (int k = 0; k < 10; ++k) o = fmaf(rx[k], lin_w[k * H + h], o);
        o += recipe_emb[(size_t)rid[n] * H + h];
        x_recipe[(size_t)n * H + h] = o;
    }
    if (n < Nu) {
        x_user[(size_t)n * H + h] = user_emb[(size_t)uid[n] * H + h];
    }
}

// ---------- SAGE layer ----------
// One wave per FOUR dst nodes. Gather phase = R4's 16-deep ILP layout, run once
// per node (unroll 1: one live gather state -> low VGPR). Epilogue = plain k-loop:
// one Wl/Wr 256B L1 load per k serves 4 nodes (W L1 traffic 32KB->8KB per node;
// it was ~190us/pass of L1 occupancy), operands via scalar wave-uniform LDS
// broadcasts, only o0..o3+wl+wr live (R6's 252-VGPR blow-up came from the
// unrolled float4 epilogue + 4 unrolled gather bodies).
template <bool RELU>
__global__ __launch_bounds__(256) void k_sage(const float* __restrict__ x_src,
                                              const float* __restrict__ x_dst,
                                              const int* __restrict__ rp,
                                              const int* __restrict__ col,
                                              const float* __restrict__ Wl,
                                              const float* __restrict__ bl,
                                              const float* __restrict__ Wr,
                                              float* __restrict__ out, int n_dst) {
    int wave = threadIdx.x >> 6, lane = threadIdx.x & 63;
    int c = lane & 15, g = lane >> 4;
    int n0 = (blockIdx.x * 4 + wave) * 4;
    __shared__ float sm[4][4][H];   // [wave][node][feature] mean
    __shared__ float sx[4][4][H];   // [wave][node][feature] x_dst

#pragma unroll 1
    for (int j = 0; j < 4; ++j) {
        int n = n0 + j;
        if (n < n_dst) {
            int beg = rp[n], end = rp[n + 1];
            float xdv = x_dst[(size_t)n * H + lane];   // hoisted: overlaps gather
            float4 a0 = make_float4(0.f, 0.f, 0.f, 0.f);
            float4 a1 = a0, a2 = a0, a3 = a0;
            int e = beg + g;
            for (; e + 12 < end; e += 16) {
                int r0 = col[e];
                int r1 = col[e + 4];
                int r2 = col[e + 8];
                int r3 = col[e + 12];
                float4 v0 = *((const float4*)(x_src + (size_t)r0 * H) + c);
                float4 v1 = *((const float4*)(x_src + (size_t)r1 * H) + c);
                float4 v2 = *((const float4*)(x_src + (size_t)r2 * H) + c);
                float4 v3 = *((const float4*)(x_src + (size_t)r3 * H) + c);
                a0.x += v0.x; a0.y += v0.y; a0.z += v0.z; a0.w += v0.w;
                a1.x += v1.x; a1.y += v1.y; a1.z += v1.z; a1.w += v1.w;
                a2.x += v2.x; a2.y += v2.y; a2.z += v2.z; a2.w += v2.w;
                a3.x += v3.x; a3.y += v3.y; a3.z += v3.z; a3.w += v3.w;
            }
            for (; e < end; e += 4) {
                int r = col[e];
                float4 v = *((const float4*)(x_src + (size_t)r * H) + c);
                a0.x += v.x; a0.y += v.y; a0.z += v.z; a0.w += v.w;
            }
            float4 acc = make_float4((a0.x + a1.x) + (a2.x + a3.x),
                                     (a0.y + a1.y) + (a2.y + a3.y),
                                     (a0.z + a1.z) + (a2.z + a3.z),
                                     (a0.w + a1.w) + (a2.w + a3.w));
#pragma unroll
            for (int off = 16; off < 64; off <<= 1) {
                acc.x += __shfl_xor(acc.x, off);
                acc.y += __shfl_xor(acc.y, off);
                acc.z += __shfl_xor(acc.z, off);
                acc.w += __shfl_xor(acc.w, off);
            }
            float inv = 1.0f / fmaxf((float)(end - beg), 1.0f);
            if (g == 0) {
                float4 mv = make_float4(acc.x * inv, acc.y * inv, acc.z * inv, acc.w * inv);
                *((float4*)&sm[wave][j][c * 4]) = mv;
            }
            sx[wave][j][lane] = xdv;
        }
    }
    __syncthreads();   // one barrier per 16 nodes

    if (n0 < n_dst) {
        float bb = bl[lane];
        float o0 = bb, o1 = bb, o2 = bb, o3 = bb;
        const float* m = &sm[wave][0][0];   // 4 rows of H, contiguous
        const float* x = &sx[wave][0][0];
#pragma unroll 4
        for (int k = 0; k < H; ++k) {
            float wl = Wl[k * H + lane];    // one 256B L1 load serves 4 nodes
            float wr = Wr[k * H + lane];
            o0 = fmaf(m[0 * H + k], wl, o0); o0 = fmaf(x[0 * H + k], wr, o0);
            o1 = fmaf(m[1 * H + k], wl, o1); o1 = fmaf(x[1 * H + k], wr, o1);
            o2 = fmaf(m[2 * H + k], wl, o2); o2 = fmaf(x[2 * H + k], wr, o2);
            o3 = fmaf(m[3 * H + k], wl, o3); o3 = fmaf(x[3 * H + k], wr, o3);
        }
        if (RELU) {
            o0 = fmaxf(o0, 0.f); o1 = fmaxf(o1, 0.f);
            o2 = fmaxf(o2, 0.f); o3 = fmaxf(o3, 0.f);
        }
        out[(size_t)n0 * H + lane] = o0;
        if (n0 + 1 < n_dst) out[(size_t)(n0 + 1) * H + lane] = o1;
        if (n0 + 2 < n_dst) out[(size_t)(n0 + 2) * H + lane] = o2;
        if (n0 + 3 < n_dst) out[(size_t)(n0 + 3) * H + lane] = o3;
    }
}

// ---------- classifier ----------
__global__ __launch_bounds__(256) void k_dot(const float* __restrict__ xu,
                                             const float* __restrict__ xr,
                                             const int* __restrict__ eli,
                                             float* __restrict__ out, int L) {
    long long w = (blockIdx.x * (long long)blockDim.x + threadIdx.x) >> 6;
    int lane = threadIdx.x & 63;
    int c = lane & 15, g = lane >> 4;
    long long e = w * 4 + g;
    if (e >= L) return;
    int a = eli[e], b = eli[(long long)L + e];
    float4 u = *((const float4*)(xu + (size_t)a * H) + c);
    float4 r = *((const float4*)(xr + (size_t)b * H) + c);
    float p = u.x * r.x;
    p = fmaf(u.y, r.y, p);
    p = fmaf(u.z, r.z, p);
    p = fmaf(u.w, r.w, p);
#pragma unroll
    for (int off = 1; off < 16; off <<= 1) p += __shfl_xor(p, off);
    if (c == 0) out[e] = p;
}

extern "C" void kernel_launch(void* const* d_in, const int* in_sizes, int n_in,
                              void* d_out, int out_size, void* d_ws, size_t ws_size,
                              hipStream_t stream) {
    const int*   uid        = (const int*)d_in[0];
    const int*   rid        = (const int*)d_in[1];
    const float* recipe_x   = (const float*)d_in[2];
    const int*   ei         = (const int*)d_in[3];
    const int*   eli        = (const int*)d_in[4];
    const float* user_emb   = (const float*)d_in[5];
    const float* recipe_emb = (const float*)d_in[6];
    const float* lin_w      = (const float*)d_in[7];
    const float* lin_b      = (const float*)d_in[8];
    const float* Wl         = (const float*)d_in[9];
    const float* bl         = (const float*)d_in[10];
    const float* Wr         = (const float*)d_in[11];

    const int Nu = in_sizes[0], Nr = in_sizes[1];
    const int E = in_sizes[3] / 2, L = in_sizes[4] / 2;
    const int nmax = (Nu > Nr) ? Nu : Nr;
    const int W = ((nmax - 1) >> WSH) + 1;   // 196 for N=200000

    char* ws = (char*)d_ws;
    size_t off = 0;
    auto alloc = [&](size_t bytes) -> char* {
        char* p = ws + off;
        off += (bytes + 255) & ~(size_t)255;
        return p;
    };
    float* x_user   = (float*)alloc((size_t)Nu * H * 4);
    float* x_recipe = (float*)alloc((size_t)Nr * H * 4);
    // overlay: y buffers (needed from sage on) share space with bin buffers (dead by then)
    size_t ybytes  = ((size_t)Nu + Nr) * H * 4;
    size_t bbytes  = (size_t)E * 8 * 2;
    char* region   = alloc(ybytes > bbytes ? ybytes : bbytes);
    float* y_user   = (float*)region;
    float* y_recipe = (float*)(region + (size_t)Nu * H * 4);
    int2* bufS = (int2*)region;
    int2* bufD = (int2*)(region + (size_t)E * 8);
    int* deg_src = (int*)alloc((size_t)Nu * 4);
    int* deg_dst = (int*)alloc((size_t)Nr * 4);
    int* rp_src  = (int*)alloc((size_t)(Nu + 1) * 4);
    int* rp_dst  = (int*)alloc((size_t)(Nr + 1) * 4);
    int* col_src = (int*)alloc((size_t)E * 4);
    int* col_dst = (int*)alloc((size_t)E * 4);
    int* winS  = (int*)alloc(MAXW * 4);      // winS..winD adjacent: one memset
    int* winD  = (int*)alloc(MAXW * 4);
    int* baseS = (int*)alloc((MAXW + 1) * 4);
    int* baseD = (int*)alloc((MAXW + 1) * 4);
    int* curS  = (int*)alloc(MAXW * 4);
    int* curD  = (int*)alloc(MAXW * 4);
    int* bsum  = (int*)alloc(4096);
    (void)ws_size; (void)n_in; (void)out_size;

    // zero window counters (ws is poisoned 0xAA)
    hipMemsetAsync(winS, 0, (size_t)2 * MAXW * 4, stream);

    // CSR build: count -> scan -> bin -> per-window deg -> rp -> per-window scatter
    k_wincount<<<1024, 256, 0, stream>>>(ei, E, winS, winD);
    k_scan_win<<<1, 256, 0, stream>>>(winS, winD, baseS, baseD, curS, curD);
    k_bin<<<(E + BINCH - 1) / BINCH, 256, 0, stream>>>(ei, E, curS, curD, bufS, bufD);
    k_degwin<<<2 * W, 256, 0, stream>>>(bufS, bufD, baseS, baseD, deg_src, deg_dst, Nu, Nr, W);

    int nb_s = (Nu + 1023) / 1024, nb_d = (Nr + 1023) / 1024;
    k_chunk_sums<<<nb_s, 256, 0, stream>>>(deg_src, Nu, bsum);
    k_scan_bsums<<<1, 256, 0, stream>>>(bsum, nb_s, rp_src, Nu);
    k_scan_final<<<nb_s, 256, 0, stream>>>(deg_src, Nu, bsum, rp_src);
    k_chunk_sums<<<nb_d, 256, 0, stream>>>(deg_dst, Nr, bsum);
    k_scan_bsums<<<1, 256, 0, stream>>>(bsum, nb_d, rp_dst, Nr);
    k_scan_final<<<nb_d, 256, 0, stream>>>(deg_dst, Nr, bsum, rp_dst);

    k_scatwin<<<2 * W, 256, 0, stream>>>(bufS, bufD, baseS, baseD, rp_src, rp_dst,
                                         col_src, col_dst, Nu, Nr, W);

    // initial features
    k_init_x<<<nmax, 64, 0, stream>>>(uid, rid, recipe_x, user_emb, recipe_emb,
                                      lin_w, lin_b, x_user, x_recipe, Nu, Nr);

    // layer 0 (+ReLU): 16 nodes per block (4 waves x 4 nodes)
    k_sage<true><<<(Nr + 15) / 16, 256, 0, stream>>>(x_user, x_recipe, rp_dst, col_dst,
                                                     Wl + 0 * H * H, bl + 0 * H, Wr + 0 * H * H,
                                                     y_recipe, Nr);
    k_sage<true><<<(Nu + 15) / 16, 256, 0, stream>>>(x_recipe, x_user, rp_src, col_src,
                                                     Wl + 1 * H * H, bl + 1 * H, Wr + 1 * H * H,
                                                     y_user, Nu);
    // layer 1 (no ReLU)
    k_sage<false><<<(Nr + 15) / 16, 256, 0, stream>>>(y_user, y_recipe, rp_dst, col_dst,
                                                      Wl + 2 * H * H, bl + 2 * H, Wr + 2 * H * H,
                                                      x_recipe, Nr);
    k_sage<false><<<(Nu + 15) / 16, 256, 0, stream>>>(y_recipe, y_user, rp_src, col_src,
                                                      Wl + 3 * H * H, bl + 3 * H, Wr + 3 * H * H,
                                                      x_user, Nu);

    // classifier
    long long nwaves = ((long long)L + 3) / 4;
    long long nblk = (nwaves + 3) / 4;
    k_dot<<<(int)nblk, 256, 0, stream>>>(x_user, x_recipe, eli, (float*)d_out, L);
}